// Round 6
// baseline (511.863 us; speedup 1.0000x reference)
//
#include <hip/hip_runtime.h>
#include <hip/hip_bf16.h>

#define NN 100000
#define NE 1600000
#define INDIM 128
#define HID 64
#define BSH 9                      // 512 nodes per bucket
#define NBUCK 196                  // ceil(NN / 512)

typedef __hip_bfloat16 bf16;
typedef unsigned short ushort;
typedef unsigned int uint;
typedef __attribute__((ext_vector_type(8))) short short8;
typedef __attribute__((ext_vector_type(4))) float floatx4;

__device__ __forceinline__ float b2f(bf16 v) { return __bfloat162float(v); }
__device__ __forceinline__ float b2f_raw(ushort u) { return __uint_as_float(((uint)u) << 16); }
__device__ __forceinline__ ushort f2bu(float v) {
    bf16 t = __float2bfloat16(v);
    return *reinterpret_cast<ushort*>(&t);
}
// flag-aware input load: f32==1 -> fp32 tensor, else bf16 tensor
__device__ __forceinline__ float ldin(const void* p, int i, int f32) {
    return f32 ? ((const float*)p)[i] : b2f(((const bf16*)p)[i]);
}
__device__ __forceinline__ float sigmoidf(float x) { return 1.f / (1.f + __expf(-x)); }
__device__ __forceinline__ float tanh_fast(float x) {
    float e = __expf(2.f * x);
    return 1.f - 2.f / (e + 1.f);
}
__device__ __forceinline__ uint4 packf8(const float* f) {
    uint4 u;
    u.x = f2bu(f[0]) | ((uint)f2bu(f[1]) << 16);
    u.y = f2bu(f[2]) | ((uint)f2bu(f[3]) << 16);
    u.z = f2bu(f[4]) | ((uint)f2bu(f[5]) << 16);
    u.w = f2bu(f[6]) | ((uint)f2bu(f[7]) << 16);
    return u;
}
// 8 consecutive elements of a (bf16|fp32) tensor as packed bf16
__device__ __forceinline__ uint4 ld8_bf16(const void* p, int off, int f32) {
    if (!f32) return *(const uint4*)((const ushort*)p + off);
    const float* q = (const float*)p + off;
    float4 a = *(const float4*)q, b = *(const float4*)(q + 4);
    float f[8] = {a.x, a.y, a.z, a.w, b.x, b.y, b.z, b.w};
    return packf8(f);
}
// 4 consecutive edge weights
__device__ __forceinline__ void ld4w(const void* ew, int e0, int f32, float* w) {
    if (f32) {
        float4 v = *(const float4*)((const float*)ew + e0);
        w[0] = v.x; w[1] = v.y; w[2] = v.z; w[3] = v.w;
    } else {
        uint2 v = *(const uint2*)((const ushort*)ew + e0);
        w[0] = b2f_raw((ushort)(v.x & 0xffff)); w[1] = b2f_raw((ushort)(v.x >> 16));
        w[2] = b2f_raw((ushort)(v.y & 0xffff)); w[3] = b2f_raw((ushort)(v.y >> 16));
    }
}

// ---------------- dtype sniffer ----------------------------------------
__global__ void k_sniff(const void* __restrict__ x, int* __restrict__ flag) {
    __shared__ int cnt;
    if (threadIdx.x == 0) cnt = 0;
    __syncthreads();
    const bf16* p = (const bf16*)x;
    int bad = 0;
    for (int i = threadIdx.x; i < 8192; i += 256) {
        float v = b2f(p[i]);
        if (!(fabsf(v) < 1e6f)) bad++;
    }
    atomicAdd(&cnt, bad);
    __syncthreads();
    if (threadIdx.x == 0) flag[0] = (cnt > 32) ? 1 : 0;
}

// ---------------- pass 1: per-bucket counts (dst bins + src bins) ------
__global__ __launch_bounds__(256)
void k_count(const int* __restrict__ ei, int* __restrict__ gcntD,
             int* __restrict__ gcntS) {
    __shared__ int hD[NBUCK], hS[NBUCK];
    for (int i = threadIdx.x; i < NBUCK; i += 256) { hD[i] = 0; hS[i] = 0; }
    __syncthreads();
    int e0 = (blockIdx.x * 256 + threadIdx.x) * 16;
    if (e0 < NE) {
        if (e0 + 16 <= NE) {
#pragma unroll
            for (int q = 0; q < 4; q++) {
                int4 s4 = *(const int4*)(ei + e0 + q * 4);
                int4 d4 = *(const int4*)(ei + NE + e0 + q * 4);
                int ss[4] = {s4.x, s4.y, s4.z, s4.w};
                int dd[4] = {d4.x, d4.y, d4.z, d4.w};
#pragma unroll
                for (int j = 0; j < 4; j++)
                    if (ss[j] != dd[j]) {
                        atomicAdd(hD + (dd[j] >> BSH), 1);
                        atomicAdd(hS + (ss[j] >> BSH), 1);
                    }
            }
        } else {
            for (int e = e0; e < NE; e++) {
                int s = ei[e], d = ei[NE + e];
                if (s != d) {
                    atomicAdd(hD + (d >> BSH), 1);
                    atomicAdd(hS + (s >> BSH), 1);
                }
            }
        }
    }
    __syncthreads();
    for (int i = threadIdx.x; i < NBUCK; i += 256) {
        if (hD[i]) atomicAdd(gcntD + i, hD[i]);
        if (hS[i]) atomicAdd(gcntS + i, hS[i]);
    }
}

// ---------------- pass 2: scan bucket counts -> bases + cursors --------
__global__ __launch_bounds__(256)
void k_scanb(const int* __restrict__ gcntD, const int* __restrict__ gcntS,
             int* __restrict__ bbaseD, int* __restrict__ bbaseS,
             int* __restrict__ gcurD, int* __restrict__ gcurS,
             int* __restrict__ rowptr) {
    __shared__ int sh[256];
    const int t = threadIdx.x;
    int v = (t < NBUCK) ? gcntD[t] : 0;
    sh[t] = v; __syncthreads();
    for (int off = 1; off < 256; off <<= 1) {
        int u = (t >= off) ? sh[t - off] : 0;
        __syncthreads(); sh[t] += u; __syncthreads();
    }
    if (t < NBUCK) { int e = sh[t] - v; bbaseD[t] = e; gcurD[t] = e; }
    if (t == 255) { bbaseD[NBUCK] = sh[255]; rowptr[NN] = sh[255]; }
    __syncthreads();
    int v2 = (t < NBUCK) ? gcntS[t] : 0;
    sh[t] = v2; __syncthreads();
    for (int off = 1; off < 256; off <<= 1) {
        int u = (t >= off) ? sh[t - off] : 0;
        __syncthreads(); sh[t] += u; __syncthreads();
    }
    if (t < NBUCK) { int e = sh[t] - v2; bbaseS[t] = e; gcurS[t] = e; }
    if (t == 255) bbaseS[NBUCK] = sh[255];
}

// ---------------- pass 3: partition edges into bucketed record streams -
// recD = {src | dlocal<<17, w}  binned by dst>>BSH
// recS = {slocal, w}            binned by src>>BSH
__global__ __launch_bounds__(256)
void k_part(const int* __restrict__ ei, const void* __restrict__ ew,
            int* __restrict__ gcurD, int* __restrict__ gcurS,
            int2* __restrict__ recD, int2* __restrict__ recS,
            const int* __restrict__ flagp) {
    const int f32 = flagp[0];
    __shared__ int cD[NBUCK], cS[NBUCK], bD[NBUCK], bS[NBUCK];
    for (int i = threadIdx.x; i < NBUCK; i += 256) { cD[i] = 0; cS[i] = 0; }
    __syncthreads();
    const int e0 = (blockIdx.x * 256 + threadIdx.x) * 8;
    int s[8], d[8], rD[8], rS[8];
    float w[8];
    bool act[8];
    if (e0 + 8 <= NE) {
        int4 sa = *(const int4*)(ei + e0), sb = *(const int4*)(ei + e0 + 4);
        int4 da = *(const int4*)(ei + NE + e0), db = *(const int4*)(ei + NE + e0 + 4);
        s[0]=sa.x; s[1]=sa.y; s[2]=sa.z; s[3]=sa.w;
        s[4]=sb.x; s[5]=sb.y; s[6]=sb.z; s[7]=sb.w;
        d[0]=da.x; d[1]=da.y; d[2]=da.z; d[3]=da.w;
        d[4]=db.x; d[5]=db.y; d[6]=db.z; d[7]=db.w;
        ld4w(ew, e0, f32, w); ld4w(ew, e0 + 4, f32, w + 4);
#pragma unroll
        for (int j = 0; j < 8; j++) act[j] = (s[j] != d[j]);
    } else {
#pragma unroll
        for (int j = 0; j < 8; j++) {
            int e = e0 + j;
            if (e < NE) {
                s[j] = ei[e]; d[j] = ei[NE + e]; w[j] = ldin(ew, e, f32);
                act[j] = (s[j] != d[j]);
            } else { s[j] = 0; d[j] = 0; w[j] = 0.f; act[j] = false; }
        }
    }
#pragma unroll
    for (int j = 0; j < 8; j++)
        if (act[j]) {
            rD[j] = atomicAdd(cD + (d[j] >> BSH), 1);
            rS[j] = atomicAdd(cS + (s[j] >> BSH), 1);
        }
    __syncthreads();
    for (int i = threadIdx.x; i < NBUCK; i += 256) {
        bD[i] = cD[i] ? atomicAdd(gcurD + i, cD[i]) : 0;
        bS[i] = cS[i] ? atomicAdd(gcurS + i, cS[i]) : 0;
    }
    __syncthreads();
#pragma unroll
    for (int j = 0; j < 8; j++)
        if (act[j]) {
            int2 pd; pd.x = s[j] | ((d[j] & 511) << 17); pd.y = __float_as_int(w[j]);
            recD[bD[d[j] >> BSH] + rD[j]] = pd;
            int2 ps; ps.x = s[j] & 511; ps.y = __float_as_int(w[j]);
            recS[bS[s[j] >> BSH] + rS[j]] = ps;
        }
}

// ---------------- pass 4: per-bucket build (all node-indexed work in LDS)
// compact CSR + rowptr + dinv, coalesced global writes.
__global__ __launch_bounds__(512)
void k_build(const int2* __restrict__ recD, const int2* __restrict__ recS,
             const int* __restrict__ bbaseD, const int* __restrict__ bbaseS,
             int* __restrict__ rowptr, int2* __restrict__ csr,
             float* __restrict__ dinv) {
    __shared__ int cnt[512], sh[512], cur[512];
    __shared__ float degf[512];
    const int t = threadIdx.x, b = blockIdx.x;
    cnt[t] = 0; degf[t] = 0.f;
    __syncthreads();
    const int dbase = bbaseD[b], dend = bbaseD[b + 1];
    const int sbase = bbaseS[b], send = bbaseS[b + 1];
    const int nD = dend - dbase, nS = send - sbase;
    const int2* rd = recD + dbase;
    const int2* rs = recS + sbase;
    for (int i = t; i < nD; i += 512) atomicAdd(cnt + (rd[i].x >> 17), 1);
    for (int i = t; i < nS; i += 512) atomicAdd(degf + rs[i].x, __int_as_float(rs[i].y));
    __syncthreads();
    const int own = cnt[t];
    sh[t] = own; __syncthreads();
    for (int off = 1; off < 512; off <<= 1) {
        int u = (t >= off) ? sh[t - off] : 0;
        __syncthreads(); sh[t] += u; __syncthreads();
    }
    const int rstart = dbase + sh[t] - own;
    cur[t] = rstart;
    const int node = (b << BSH) + t;
    if (node < NN) {
        rowptr[node] = rstart;
        float dg = degf[t];
        dinv[node] = dg > 0.f ? rsqrtf(dg) : 0.f;
    }
    __syncthreads();
    for (int i = t; i < nD; i += 512) {
        int2 r = rd[i];
        int pos = atomicAdd(cur + (r.x >> 17), 1);
        int2 o; o.x = r.x & 0x1FFFF; o.y = r.y;
        csr[pos] = o;
    }
}

// ---------------- gather SpMM: one wave per dst, register accumulate ---
// agg = -dinv[dst] * sum_e dinv[src_e] * w_e * z[src_e]
// MODE 0: z = h (flag dtype, stride 64)   -> Tx1 = agg, bf16 stride-128
// MODE 1: z = Tx1 (bf16 stride-128 rows)  -> Tx2 = 2*agg - h, bf16 stride-128
template<int MODE>
__global__ __launch_bounds__(256)
void k_gath(const int* __restrict__ rowptr, const float* __restrict__ dinv,
            const int2* __restrict__ csr, const void* __restrict__ zin,
            const void* __restrict__ hin, ushort* __restrict__ outv,
            const int* __restrict__ flagp) {
    const int f32 = flagp[0];
    int n = (blockIdx.x * 256 + threadIdx.x) >> 6;   // dst node
    int lane = threadIdx.x & 63;
    if (n >= NN) return;
    int b0 = rowptr[n], e0 = rowptr[n + 1];
    const int2* row = csr + b0;
    int cnt = e0 - b0;
    float acc = 0.f;
    int i = 0;
#define ZLD(sidx) (MODE == 0 ? ldin(zin, (sidx) * 64 + lane, f32) \
                             : b2f_raw(((const ushort*)zin)[(size_t)(sidx) * 128 + lane]))
    for (; i + 3 < cnt; i += 4) {
        int2 p0 = row[i], p1 = row[i + 1], p2 = row[i + 2], p3 = row[i + 3];
        float z0 = ZLD(p0.x), z1 = ZLD(p1.x), z2 = ZLD(p2.x), z3 = ZLD(p3.x);
        acc = fmaf(dinv[p0.x] * __int_as_float(p0.y), z0, acc);
        acc = fmaf(dinv[p1.x] * __int_as_float(p1.y), z1, acc);
        acc = fmaf(dinv[p2.x] * __int_as_float(p2.y), z2, acc);
        acc = fmaf(dinv[p3.x] * __int_as_float(p3.y), z3, acc);
    }
    for (; i < cnt; i++) {
        int2 p0 = row[i];
        float z0 = ZLD(p0.x);
        acc = fmaf(dinv[p0.x] * __int_as_float(p0.y), z0, acc);
    }
#undef ZLD
    float r = -dinv[n] * acc;
    if (MODE == 0) {
        outv[(size_t)n * 128 + lane] = f2bu(r);
    } else {
        float hv = ldin(hin, n * 64 + lane, f32);        // coalesced
        outv[(size_t)n * 128 + lane] = f2bu(2.f * r - hv);
    }
}

// ---------------- pre-swizzle weights into MFMA fragment order ---------
// Wf: [kc 0..9][t 0..15][lane 0..63][j 0..7] bf16, element =
//     W[r = kc*32 + (lane>>4)*8 + j][o = 16t + (lane&15)] with column perm
//     o = 16t+(l&15): gate g = t&3, cc = (t>>2)*16 + (lane&15)
// WlF: [kc2 0..1][t 0..3][lane][j], Wl[k = kc2*32+(l>>4)*8+j][n = 16t+(l&15)]
// biasP[o]: permuted bias
__global__ void k_wcat(const void* __restrict__ Wx, const void* __restrict__ theta,
                       const void* __restrict__ bg, const void* __restrict__ convb,
                       const void* __restrict__ Wl,
                       ushort* __restrict__ Wf, float* __restrict__ biasP,
                       ushort* __restrict__ WlF, const int* __restrict__ flagp) {
    const int f32 = flagp[0];
    int gid = blockIdx.x * 256 + threadIdx.x;   // 336 blocks * 256 = 86016
    if (gid < 81920) {
        int j = gid & 7, l = (gid >> 3) & 63, tile = gid >> 9;
        int kc = tile >> 4, t = tile & 15;
        int r = kc * 32 + ((l >> 4) * 8) + j;
        int g = t & 3;
        int cc = (t >> 2) * 16 + (l & 15);
        float v;
        if (r < 128) {
            v = ldin(Wx, (g * 128 + r) * 64 + cc, f32);
        } else {
            int k3 = (r - 128) >> 6, rr = (r - 128) & 63;
            v = ldin(theta, ((g * 3 + k3) * 64 + rr) * 64 + cc, f32);
        }
        Wf[gid] = f2bu(v);
        if (gid < 256) {
            int o = gid;
            int gg = (o >> 4) & 3;
            int cc2 = (o >> 6) * 16 + (o & 15);
            biasP[o] = ldin(bg, gg * 64 + cc2, f32) + ldin(convb, gg * 64 + cc2, f32);
        }
    } else {
        int gid2 = gid - 81920;                  // [0, 4096)
        int j = gid2 & 7, l = (gid2 >> 3) & 63, tile2 = gid2 >> 9;
        int kc2 = tile2 >> 2, t = tile2 & 3;
        int k = kc2 * 32 + ((l >> 4) * 8) + j;
        int n = t * 16 + (l & 15);
        WlF[gid2] = f2bu(ldin(Wl, k * 64 + n, f32));
    }
}

// ---------------- MFMA gate GEMM [64 nodes x 256 cols] + LSTM + out ----
// F rows: 0-127 x | 128-191 h | 192-255 Tx1 | 256-319 Tx2
// NO LDS staging: each lane loads its A-fragment directly from global
// (node = base + mt*16 + (lane&15), cols kc*32 + (lane>>4)*8). A data is
// read 4x (once per wave) from L2 — cheap — and the K-loop has ZERO
// barriers, so all 80 loads/wave schedule freely against 160 MFMAs.
// Aliasing: Tx1 (bf16) lives in the `out` region, Tx2 in the `c0` region,
// per-node byte ranges inside the node's own output slab. The single
// __syncthreads after the K-loop (vmcnt(0) drain) guarantees all aliased
// reads complete before any epilogue write. Blocks touch only their slab.
__global__ __launch_bounds__(256)
void k_gates(const void* __restrict__ x, const void* __restrict__ h,
             const void* __restrict__ cin,
             const ushort* __restrict__ Tx1, const ushort* __restrict__ Tx2,
             const ushort* __restrict__ Wf, const float* __restrict__ biasP,
             const ushort* __restrict__ WlF, const void* __restrict__ bl,
             float* __restrict__ outF, float* __restrict__ h0o,
             float* __restrict__ c0o, const int* __restrict__ flagp) {
    const int f32 = flagp[0];
    __shared__ ushort Hs[64 * 72];       // 9.2 KB, relu(h0) bf16, padded stride 72
    const int tid = threadIdx.x;
    const int lane = tid & 63;
    const int w = tid >> 6;              // wave 0..3
    const int base = blockIdx.x * 64;
    const int rown = lane & 15;          // row within 16-row m-tile
    const int kq = lane >> 4;            // k-quad (8-elem group within 32)

    floatx4 acc[4][4];                   // [m-tile][gate]
    {
        float bv0 = biasP[w * 64 + 0 * 16 + (lane & 15)];
        float bv1 = biasP[w * 64 + 1 * 16 + (lane & 15)];
        float bv2 = biasP[w * 64 + 2 * 16 + (lane & 15)];
        float bv3 = biasP[w * 64 + 3 * 16 + (lane & 15)];
#pragma unroll
        for (int mt = 0; mt < 4; mt++) {
            acc[mt][0] = (floatx4){bv0, bv0, bv0, bv0};
            acc[mt][1] = (floatx4){bv1, bv1, bv1, bv1};
            acc[mt][2] = (floatx4){bv2, bv2, bv2, bv2};
            acc[mt][3] = (floatx4){bv3, bv3, bv3, bv3};
        }
    }

    // direct per-lane A-fragment load (8 bf16)
    auto lda = [&](int mt, int kc) -> short8 {
        int node = base + mt * 16 + rown;
        uint4 r = {0, 0, 0, 0};
        if (node < NN) {
            if (kc < 4)      r = ld8_bf16(x, node * 128 + kc * 32 + kq * 8, f32);
            else if (kc < 6) r = ld8_bf16(h, node * 64 + (kc - 4) * 32 + kq * 8, f32);
            else if (kc < 8) r = *(const uint4*)&Tx1[(size_t)node * 128 + (kc - 6) * 32 + kq * 8];
            else             r = *(const uint4*)&Tx2[(size_t)node * 128 + (kc - 8) * 32 + kq * 8];
        }
        return *(short8*)&r;
    };

#pragma unroll
    for (int kc = 0; kc < 10; kc++) {
        short8 aF[4];
#pragma unroll
        for (int mt = 0; mt < 4; mt++) aF[mt] = lda(mt, kc);
        short8 bF[4];
#pragma unroll
        for (int g = 0; g < 4; g++)
            bF[g] = *(const short8*)&Wf[((kc * 16 + w * 4 + g) * 64 + lane) * 8];
#pragma unroll
        for (int mt = 0; mt < 4; mt++)
#pragma unroll
            for (int g = 0; g < 4; g++)
                acc[mt][g] = __builtin_amdgcn_mfma_f32_16x16x32_bf16(
                    aF[mt], bF[g], acc[mt][g], 0, 0, 0);
    }

    __syncthreads();   // vmcnt(0) drain: all Tx1/Tx2 reads done before writes

    // ---- LSTM epilogue, fully in-register (perm put all 4 gates here) ----
    const int cc = w * 16 + (lane & 15);
#pragma unroll
    for (int mt = 0; mt < 4; mt++) {
        const int m0 = mt * 16 + ((lane >> 4) * 4);
#pragma unroll
        for (int r = 0; r < 4; r++) {
            int ml = m0 + r;
            int node = base + ml;
            float gi = sigmoidf(acc[mt][0][r]);
            float gf = sigmoidf(acc[mt][1][r]);
            float gt = tanh_fast(acc[mt][2][r]);
            float go = sigmoidf(acc[mt][3][r]);
            float cv = (node < NN) ? ldin(cin, node * 64 + cc, f32) : 0.f;
            float c0 = gf * cv + gi * gt;
            float h0v = go * tanh_fast(c0);
            if (node < NN) {
                c0o[node * 64 + cc] = c0;
                h0o[node * 64 + cc] = h0v;
            }
            Hs[ml * 72 + cc] = f2bu(fmaxf(h0v, 0.f));
        }
    }
    __syncthreads();

    // ---- fused out = relu(h0) @ Wl + bl (8 MFMA per wave) ----
    float blv = ldin(bl, w * 16 + (lane & 15), f32);
    floatx4 oacc[4];
#pragma unroll
    for (int mt = 0; mt < 4; mt++) oacc[mt] = (floatx4){blv, blv, blv, blv};
#pragma unroll
    for (int kc2 = 0; kc2 < 2; kc2++) {
        short8 bW = *(const short8*)&WlF[((kc2 * 4 + w) * 64 + lane) * 8];
#pragma unroll
        for (int mt = 0; mt < 4; mt++) {
            short8 aH = *(const short8*)&Hs[(mt * 16 + (lane & 15)) * 72
                                            + kc2 * 32 + (lane >> 4) * 8];
            oacc[mt] = __builtin_amdgcn_mfma_f32_16x16x32_bf16(
                aH, bW, oacc[mt], 0, 0, 0);
        }
    }
#pragma unroll
    for (int mt = 0; mt < 4; mt++) {
        const int m0 = mt * 16 + ((lane >> 4) * 4);
#pragma unroll
        for (int r = 0; r < 4; r++) {
            int node = base + m0 + r;
            if (node < NN)
                outF[node * 64 + w * 16 + (lane & 15)] = oacc[mt][r];
        }
    }
}

extern "C" void kernel_launch(void* const* d_in, const int* in_sizes, int n_in,
                              void* d_out, int out_size, void* d_ws, size_t ws_size,
                              hipStream_t stream) {
    const void* x     = d_in[0];
    const int*  ei    = (const int*)d_in[1];
    const void* ew    = d_in[2];
    const void* h     = d_in[3];
    const void* c     = d_in[4];
    const void* Wx    = d_in[5];
    const void* bg    = d_in[6];
    const void* theta = d_in[7];
    const void* convb = d_in[8];
    const void* Wl    = d_in[9];
    const void* bl    = d_in[10];
    (void)in_sizes; (void)n_in; (void)out_size; (void)ws_size;

    // ws layout (4B words) — ~1.78 MB total
    float*  ws     = (float*)d_ws;
    int*    flag   = (int*)ws;                 // 64
    float*  dinv   = ws + 64;                  // 100000
    int*    rowptr = (int*)(ws + 100064);      // 100001 (pad to 100064)
    int*    gcntD  = (int*)(ws + 200128);      // 256
    int*    gcntS  = (int*)(ws + 200384);      // 256
    int*    bbaseD = (int*)(ws + 200640);      // 197 (pad 256)
    int*    bbaseS = (int*)(ws + 200896);      // 197
    int*    gcurD  = (int*)(ws + 201152);      // 256
    int*    gcurS  = (int*)(ws + 201408);      // 256
    float*  biasP  = ws + 400128;              // 256
    ushort* Wf     = (ushort*)(ws + 400384);   // 81920 ushort = 40960 words
    ushort* WlF    = (ushort*)(ws + 441344);   // 4096 ushort = 2048 words

    // d_out FP32: out [0,6.4M) | h0 [6.4M,12.8M) | c0 [12.8M,19.2M)  (words)
    float* outF = (float*)d_out;
    float* h0o  = outF + (size_t)NN * 64;
    float* c0o  = outF + (size_t)2 * NN * 64;
    // Tx1 bf16 aliases the out region; Tx2 bf16 aliases the c0 region —
    // node n occupies ushort [n*128, n*128+64) = bytes [n*256, n*256+128),
    // inside node n's own output slab.
    ushort* Tx1b = (ushort*)outF;
    ushort* Tx2b = (ushort*)c0o;
    // h0 region (6.4M words): recD [0,3.2M) + csr [3.2M,6.4M)
    //   recD written by k_part, read by k_build; csr written by k_build,
    //   read by gaths; whole region overwritten by k_gates h0 at the end.
    int2* recD = (int2*)h0o;
    int2* csr  = (int2*)(h0o + 3200000);
    // c0 region: recS [0,3.2M) — dead after k_build, then Tx2 overwrites.
    int2* recS = (int2*)c0o;

    k_sniff<<<1, 256, 0, stream>>>(x, flag);
    hipMemsetAsync(gcntD, 0, 512 * 4, stream);   // gcntD + gcntS

    k_count<<<(NE + 4095) / 4096, 256, 0, stream>>>(ei, gcntD, gcntS);
    k_scanb<<<1, 256, 0, stream>>>(gcntD, gcntS, bbaseD, bbaseS, gcurD, gcurS, rowptr);
    k_part<<<(NE + 2047) / 2048, 256, 0, stream>>>(ei, ew, gcurD, gcurS,
                                                   recD, recS, flag);
    k_build<<<NBUCK, 512, 0, stream>>>(recD, recS, bbaseD, bbaseS,
                                       rowptr, csr, dinv);
    k_wcat<<<336, 256, 0, stream>>>(Wx, theta, bg, convb, Wl, Wf, biasP, WlF, flag);

    k_gath<0><<<25000, 256, 0, stream>>>(rowptr, dinv, csr, h,    h, Tx1b, flag);
    k_gath<1><<<25000, 256, 0, stream>>>(rowptr, dinv, csr, Tx1b, h, Tx2b, flag);

    k_gates<<<(NN + 63) / 64, 256, 0, stream>>>(x, h, c, Tx1b, Tx2b,
                                                Wf, biasP, WlF, bl,
                                                outF, h0o, c0o, flag);
}

// Round 7
// 426.714 us; speedup vs baseline: 1.1995x; 1.1995x over previous
//
#include <hip/hip_runtime.h>
#include <hip/hip_bf16.h>

#define NN 100000
#define NE 1600000
#define INDIM 128
#define HID 64
#define BSH 9                      // 512 nodes per bucket
#define NBUCK 196                  // ceil(NN / 512)

typedef __hip_bfloat16 bf16;
typedef unsigned short ushort;
typedef unsigned int uint;
typedef __attribute__((ext_vector_type(8))) short short8;
typedef __attribute__((ext_vector_type(4))) float floatx4;

__device__ __forceinline__ float b2f(bf16 v) { return __bfloat162float(v); }
__device__ __forceinline__ float b2f_raw(ushort u) { return __uint_as_float(((uint)u) << 16); }
__device__ __forceinline__ ushort f2bu(float v) {
    bf16 t = __float2bfloat16(v);
    return *reinterpret_cast<ushort*>(&t);
}
// flag-aware input load: f32==1 -> fp32 tensor, else bf16 tensor
__device__ __forceinline__ float ldin(const void* p, int i, int f32) {
    return f32 ? ((const float*)p)[i] : b2f(((const bf16*)p)[i]);
}
__device__ __forceinline__ float sigmoidf(float x) { return 1.f / (1.f + __expf(-x)); }
__device__ __forceinline__ float tanh_fast(float x) {
    float e = __expf(2.f * x);
    return 1.f - 2.f / (e + 1.f);
}
__device__ __forceinline__ uint4 packf8(const float* f) {
    uint4 u;
    u.x = f2bu(f[0]) | ((uint)f2bu(f[1]) << 16);
    u.y = f2bu(f[2]) | ((uint)f2bu(f[3]) << 16);
    u.z = f2bu(f[4]) | ((uint)f2bu(f[5]) << 16);
    u.w = f2bu(f[6]) | ((uint)f2bu(f[7]) << 16);
    return u;
}
// 8 consecutive elements of a (bf16|fp32) tensor as packed bf16
__device__ __forceinline__ uint4 ld8_bf16(const void* p, int off, int f32) {
    if (!f32) return *(const uint4*)((const ushort*)p + off);
    const float* q = (const float*)p + off;
    float4 a = *(const float4*)q, b = *(const float4*)(q + 4);
    float f[8] = {a.x, a.y, a.z, a.w, b.x, b.y, b.z, b.w};
    return packf8(f);
}
// 4 consecutive edge weights
__device__ __forceinline__ void ld4w(const void* ew, int e0, int f32, float* w) {
    if (f32) {
        float4 v = *(const float4*)((const float*)ew + e0);
        w[0] = v.x; w[1] = v.y; w[2] = v.z; w[3] = v.w;
    } else {
        uint2 v = *(const uint2*)((const ushort*)ew + e0);
        w[0] = b2f_raw((ushort)(v.x & 0xffff)); w[1] = b2f_raw((ushort)(v.x >> 16));
        w[2] = b2f_raw((ushort)(v.y & 0xffff)); w[3] = b2f_raw((ushort)(v.y >> 16));
    }
}
// async global->LDS, 16 bytes per lane, zero VGPR round-trip
__device__ __forceinline__ void gl_lds16(const void* g, void* l) {
    __builtin_amdgcn_global_load_lds(
        (const __attribute__((address_space(1))) unsigned int*)g,
        (__attribute__((address_space(3))) unsigned int*)l, 16, 0, 0);
}

// ---------------- dtype sniffer ----------------------------------------
__global__ void k_sniff(const void* __restrict__ x, int* __restrict__ flag) {
    __shared__ int cnt;
    if (threadIdx.x == 0) cnt = 0;
    __syncthreads();
    const bf16* p = (const bf16*)x;
    int bad = 0;
    for (int i = threadIdx.x; i < 8192; i += 256) {
        float v = b2f(p[i]);
        if (!(fabsf(v) < 1e6f)) bad++;
    }
    atomicAdd(&cnt, bad);
    __syncthreads();
    if (threadIdx.x == 0) flag[0] = (cnt > 32) ? 1 : 0;
}

// ---------------- pass 1: per-bucket counts (dst bins + src bins) ------
__global__ __launch_bounds__(256)
void k_count(const int* __restrict__ ei, int* __restrict__ gcntD,
             int* __restrict__ gcntS) {
    __shared__ int hD[NBUCK], hS[NBUCK];
    for (int i = threadIdx.x; i < NBUCK; i += 256) { hD[i] = 0; hS[i] = 0; }
    __syncthreads();
    int e0 = (blockIdx.x * 256 + threadIdx.x) * 16;
    if (e0 < NE) {
        if (e0 + 16 <= NE) {
#pragma unroll
            for (int q = 0; q < 4; q++) {
                int4 s4 = *(const int4*)(ei + e0 + q * 4);
                int4 d4 = *(const int4*)(ei + NE + e0 + q * 4);
                int ss[4] = {s4.x, s4.y, s4.z, s4.w};
                int dd[4] = {d4.x, d4.y, d4.z, d4.w};
#pragma unroll
                for (int j = 0; j < 4; j++)
                    if (ss[j] != dd[j]) {
                        atomicAdd(hD + (dd[j] >> BSH), 1);
                        atomicAdd(hS + (ss[j] >> BSH), 1);
                    }
            }
        } else {
            for (int e = e0; e < NE; e++) {
                int s = ei[e], d = ei[NE + e];
                if (s != d) {
                    atomicAdd(hD + (d >> BSH), 1);
                    atomicAdd(hS + (s >> BSH), 1);
                }
            }
        }
    }
    __syncthreads();
    for (int i = threadIdx.x; i < NBUCK; i += 256) {
        if (hD[i]) atomicAdd(gcntD + i, hD[i]);
        if (hS[i]) atomicAdd(gcntS + i, hS[i]);
    }
}

// ---------------- pass 2: scan bucket counts -> bases + cursors --------
__global__ __launch_bounds__(256)
void k_scanb(const int* __restrict__ gcntD, const int* __restrict__ gcntS,
             int* __restrict__ bbaseD, int* __restrict__ bbaseS,
             int* __restrict__ gcurD, int* __restrict__ gcurS,
             int* __restrict__ rowptr) {
    __shared__ int sh[256];
    const int t = threadIdx.x;
    int v = (t < NBUCK) ? gcntD[t] : 0;
    sh[t] = v; __syncthreads();
    for (int off = 1; off < 256; off <<= 1) {
        int u = (t >= off) ? sh[t - off] : 0;
        __syncthreads(); sh[t] += u; __syncthreads();
    }
    if (t < NBUCK) { int e = sh[t] - v; bbaseD[t] = e; gcurD[t] = e; }
    if (t == 255) { bbaseD[NBUCK] = sh[255]; rowptr[NN] = sh[255]; }
    __syncthreads();
    int v2 = (t < NBUCK) ? gcntS[t] : 0;
    sh[t] = v2; __syncthreads();
    for (int off = 1; off < 256; off <<= 1) {
        int u = (t >= off) ? sh[t - off] : 0;
        __syncthreads(); sh[t] += u; __syncthreads();
    }
    if (t < NBUCK) { int e = sh[t] - v2; bbaseS[t] = e; gcurS[t] = e; }
    if (t == 255) bbaseS[NBUCK] = sh[255];
}

// ---------------- pass 3: partition edges into bucketed record streams -
// recD = {src | dlocal<<17, w}  binned by dst>>BSH
// recS = {slocal, w}            binned by src>>BSH
__global__ __launch_bounds__(256)
void k_part(const int* __restrict__ ei, const void* __restrict__ ew,
            int* __restrict__ gcurD, int* __restrict__ gcurS,
            int2* __restrict__ recD, int2* __restrict__ recS,
            const int* __restrict__ flagp) {
    const int f32 = flagp[0];
    __shared__ int cD[NBUCK], cS[NBUCK], bD[NBUCK], bS[NBUCK];
    for (int i = threadIdx.x; i < NBUCK; i += 256) { cD[i] = 0; cS[i] = 0; }
    __syncthreads();
    const int e0 = (blockIdx.x * 256 + threadIdx.x) * 8;
    int s[8], d[8], rD[8], rS[8];
    float w[8];
    bool act[8];
    if (e0 + 8 <= NE) {
        int4 sa = *(const int4*)(ei + e0), sb = *(const int4*)(ei + e0 + 4);
        int4 da = *(const int4*)(ei + NE + e0), db = *(const int4*)(ei + NE + e0 + 4);
        s[0]=sa.x; s[1]=sa.y; s[2]=sa.z; s[3]=sa.w;
        s[4]=sb.x; s[5]=sb.y; s[6]=sb.z; s[7]=sb.w;
        d[0]=da.x; d[1]=da.y; d[2]=da.z; d[3]=da.w;
        d[4]=db.x; d[5]=db.y; d[6]=db.z; d[7]=db.w;
        ld4w(ew, e0, f32, w); ld4w(ew, e0 + 4, f32, w + 4);
#pragma unroll
        for (int j = 0; j < 8; j++) act[j] = (s[j] != d[j]);
    } else {
#pragma unroll
        for (int j = 0; j < 8; j++) {
            int e = e0 + j;
            if (e < NE) {
                s[j] = ei[e]; d[j] = ei[NE + e]; w[j] = ldin(ew, e, f32);
                act[j] = (s[j] != d[j]);
            } else { s[j] = 0; d[j] = 0; w[j] = 0.f; act[j] = false; }
        }
    }
#pragma unroll
    for (int j = 0; j < 8; j++)
        if (act[j]) {
            rD[j] = atomicAdd(cD + (d[j] >> BSH), 1);
            rS[j] = atomicAdd(cS + (s[j] >> BSH), 1);
        }
    __syncthreads();
    for (int i = threadIdx.x; i < NBUCK; i += 256) {
        bD[i] = cD[i] ? atomicAdd(gcurD + i, cD[i]) : 0;
        bS[i] = cS[i] ? atomicAdd(gcurS + i, cS[i]) : 0;
    }
    __syncthreads();
#pragma unroll
    for (int j = 0; j < 8; j++)
        if (act[j]) {
            int2 pd; pd.x = s[j] | ((d[j] & 511) << 17); pd.y = __float_as_int(w[j]);
            recD[bD[d[j] >> BSH] + rD[j]] = pd;
            int2 ps; ps.x = s[j] & 511; ps.y = __float_as_int(w[j]);
            recS[bS[s[j] >> BSH] + rS[j]] = ps;
        }
}

// ---------------- pass 4: per-bucket build (all node-indexed work in LDS)
// compact CSR + rowptr + dinv, coalesced global writes.
__global__ __launch_bounds__(512)
void k_build(const int2* __restrict__ recD, const int2* __restrict__ recS,
             const int* __restrict__ bbaseD, const int* __restrict__ bbaseS,
             int* __restrict__ rowptr, int2* __restrict__ csr,
             float* __restrict__ dinv) {
    __shared__ int cnt[512], sh[512], cur[512];
    __shared__ float degf[512];
    const int t = threadIdx.x, b = blockIdx.x;
    cnt[t] = 0; degf[t] = 0.f;
    __syncthreads();
    const int dbase = bbaseD[b], dend = bbaseD[b + 1];
    const int sbase = bbaseS[b], send = bbaseS[b + 1];
    const int nD = dend - dbase, nS = send - sbase;
    const int2* rd = recD + dbase;
    const int2* rs = recS + sbase;
    for (int i = t; i < nD; i += 512) atomicAdd(cnt + (rd[i].x >> 17), 1);
    for (int i = t; i < nS; i += 512) atomicAdd(degf + rs[i].x, __int_as_float(rs[i].y));
    __syncthreads();
    const int own = cnt[t];
    sh[t] = own; __syncthreads();
    for (int off = 1; off < 512; off <<= 1) {
        int u = (t >= off) ? sh[t - off] : 0;
        __syncthreads(); sh[t] += u; __syncthreads();
    }
    const int rstart = dbase + sh[t] - own;
    cur[t] = rstart;
    const int node = (b << BSH) + t;
    if (node < NN) {
        rowptr[node] = rstart;
        float dg = degf[t];
        dinv[node] = dg > 0.f ? rsqrtf(dg) : 0.f;
    }
    __syncthreads();
    for (int i = t; i < nD; i += 512) {
        int2 r = rd[i];
        int pos = atomicAdd(cur + (r.x >> 17), 1);
        int2 o; o.x = r.x & 0x1FFFF; o.y = r.y;
        csr[pos] = o;
    }
}

// ---------------- gather SpMM: one wave per dst, register accumulate ---
// agg = -dinv[dst] * sum_e dinv[src_e] * w_e * z[src_e]
// Lanes cooperatively load <=64 csr entries in ONE coalesced read and
// pre-scale dinv[src]*w lane-parallel; per-edge values are shfl-broadcast,
// so the z-row loads issue back-to-back (no csr->z dependent chain).
// Same accumulation order as before -> bit-identical results.
// MODE 0: z = h (flag dtype, stride 64)   -> Tx1 = agg, bf16 stride-128
// MODE 1: z = Tx1 (bf16 stride-128 rows)  -> Tx2 = 2*agg - h, bf16 stride-128
template<int MODE>
__global__ __launch_bounds__(256)
void k_gath(const int* __restrict__ rowptr, const float* __restrict__ dinv,
            const int2* __restrict__ csr, const void* __restrict__ zin,
            const void* __restrict__ hin, ushort* __restrict__ outv,
            const int* __restrict__ flagp) {
    const int f32 = flagp[0];
    int n = (blockIdx.x * 256 + threadIdx.x) >> 6;   // dst node
    int lane = threadIdx.x & 63;
    if (n >= NN) return;
    int b0 = rowptr[n], e0r = rowptr[n + 1];
    int cnt = e0r - b0;
    const int2* row = csr + b0;
    float acc = 0.f;
#define ZLD(sidx) (MODE == 0 ? ldin(zin, (sidx) * 64 + lane, f32) \
                             : b2f_raw(((const ushort*)zin)[(size_t)(sidx) * 128 + lane]))
    for (int ib = 0; ib < cnt; ib += 64) {
        int idx = ib + lane;
        int2 p;
        if (idx < cnt) p = row[idx];
        else { p.x = 0; p.y = 0; }
        float sw = dinv[p.x] * __int_as_float(p.y);   // 0 for inactive lanes
        int m = cnt - ib; if (m > 64) m = 64;
        int m4 = (m + 3) & ~3;
        for (int e = 0; e < m4; e += 4) {
            int   s0 = __shfl(p.x, e),     s1 = __shfl(p.x, e + 1);
            int   s2 = __shfl(p.x, e + 2), s3 = __shfl(p.x, e + 3);
            float w0 = __shfl(sw, e),      w1 = __shfl(sw, e + 1);
            float w2 = __shfl(sw, e + 2),  w3 = __shfl(sw, e + 3);
            float z0 = ZLD(s0), z1 = ZLD(s1), z2 = ZLD(s2), z3 = ZLD(s3);
            acc = fmaf(w0, z0, acc);
            acc = fmaf(w1, z1, acc);
            acc = fmaf(w2, z2, acc);
            acc = fmaf(w3, z3, acc);
        }
    }
#undef ZLD
    float r = -dinv[n] * acc;
    if (MODE == 0) {
        outv[(size_t)n * 128 + lane] = f2bu(r);
    } else {
        float hv = ldin(hin, n * 64 + lane, f32);        // coalesced
        outv[(size_t)n * 128 + lane] = f2bu(2.f * r - hv);
    }
}

// ---------------- pre-swizzle weights into MFMA fragment order ---------
// Wf: [kc 0..9][t 0..15][lane 0..63][j 0..7] bf16, element =
//     W[r = kc*32 + (lane>>4)*8 + j][o = 16t + (lane&15)] with column perm
//     o = 16t+(l&15): gate g = t&3, cc = (t>>2)*16 + (lane&15)
// WlF: [kc2 0..1][t 0..3][lane][j], Wl[k = kc2*32+(l>>4)*8+j][n = 16t+(l&15)]
// biasP[o]: permuted bias
__global__ void k_wcat(const void* __restrict__ Wx, const void* __restrict__ theta,
                       const void* __restrict__ bg, const void* __restrict__ convb,
                       const void* __restrict__ Wl,
                       ushort* __restrict__ Wf, float* __restrict__ biasP,
                       ushort* __restrict__ WlF, const int* __restrict__ flagp) {
    const int f32 = flagp[0];
    int gid = blockIdx.x * 256 + threadIdx.x;   // 336 blocks * 256 = 86016
    if (gid < 81920) {
        int j = gid & 7, l = (gid >> 3) & 63, tile = gid >> 9;
        int kc = tile >> 4, t = tile & 15;
        int r = kc * 32 + ((l >> 4) * 8) + j;
        int g = t & 3;
        int cc = (t >> 2) * 16 + (l & 15);
        float v;
        if (r < 128) {
            v = ldin(Wx, (g * 128 + r) * 64 + cc, f32);
        } else {
            int k3 = (r - 128) >> 6, rr = (r - 128) & 63;
            v = ldin(theta, ((g * 3 + k3) * 64 + rr) * 64 + cc, f32);
        }
        Wf[gid] = f2bu(v);
        if (gid < 256) {
            int o = gid;
            int gg = (o >> 4) & 3;
            int cc2 = (o >> 6) * 16 + (o & 15);
            biasP[o] = ldin(bg, gg * 64 + cc2, f32) + ldin(convb, gg * 64 + cc2, f32);
        }
    } else {
        int gid2 = gid - 81920;                  // [0, 4096)
        int j = gid2 & 7, l = (gid2 >> 3) & 63, tile2 = gid2 >> 9;
        int kc2 = tile2 >> 2, t = tile2 & 3;
        int k = kc2 * 32 + ((l >> 4) * 8) + j;
        int n = t * 16 + (l & 15);
        WlF[gid2] = f2bu(ldin(Wl, k * 64 + n, f32));
    }
}

// ---------------- MFMA gate GEMM [64 nodes x 256 cols] + LSTM + out ----
// F rows: 0-127 x | 128-191 h | 192-255 Tx1 | 256-319 Tx2
// The ENTIRE 40 KB A-panel (64 nodes x 320 k) is staged up-front via
// global_load_lds (16B/lane, zero VGPR): 10 fire-and-forget loads per
// thread, all in flight simultaneously; ONE barrier; then 160 MFMAs run
// against LDS with no further syncs. Hs reuses the (then dead) As space.
// As slot b (of 256 per chunk): mt=b>>6, l=b&63 -> node base+mt*16+(l&15),
// cols kc*32+(l>>4)*8 -> staging thread t stages slot t (lds = base+t*16,
// wave-uniform base + lane*16: the required global_load_lds layout).
// Aliasing: Tx1 lives in `out`, Tx2 in `c0` (per-node slabs); all aliased
// global reads complete at the pre-K-loop barrier (vmcnt drain), long
// before epilogue writes. Blocks touch only their own 64-node slab.
__global__ __launch_bounds__(256)
void k_gates(const void* __restrict__ x, const void* __restrict__ h,
             const void* __restrict__ cin,
             const ushort* __restrict__ Tx1, const ushort* __restrict__ Tx2,
             const ushort* __restrict__ Wf, const float* __restrict__ biasP,
             const ushort* __restrict__ WlF, const void* __restrict__ bl,
             float* __restrict__ outF, float* __restrict__ h0o,
             float* __restrict__ c0o, const int* __restrict__ flagp) {
    const int f32 = flagp[0];
    __shared__ ushort As[10 * 256 * 8];  // 40 KB; reused as Hs after K-loop
    const int tid = threadIdx.x;
    const int lane = tid & 63;
    const int w = tid >> 6;              // wave 0..3
    const int base = blockIdx.x * 64;

    // staging role: thread t -> slot t of each chunk
    const int nodeS = base + ((tid >> 6) << 4) + (tid & 15);
    const int kq8 = ((tid >> 4) & 3) * 8;
    const bool okS = nodeS < NN;

    if (!f32) {
        if (okS) {
#pragma unroll
            for (int kc = 0; kc < 10; kc++) {
                const ushort* g;
                if (kc < 4)      g = (const ushort*)x + (size_t)nodeS * 128 + kc * 32 + kq8;
                else if (kc < 6) g = (const ushort*)h + (size_t)nodeS * 64 + (kc - 4) * 32 + kq8;
                else if (kc < 8) g = Tx1 + (size_t)nodeS * 128 + (kc - 6) * 32 + kq8;
                else             g = Tx2 + (size_t)nodeS * 128 + (kc - 8) * 32 + kq8;
                gl_lds16(g, &As[(kc * 256 + tid) * 8]);
            }
        }
    } else {
#pragma unroll
        for (int kc = 0; kc < 10; kc++) {
            uint4 raw = {0, 0, 0, 0};
            if (okS) {
                if (kc < 4)      raw = ld8_bf16(x, nodeS * 128 + kc * 32 + kq8, 1);
                else if (kc < 6) raw = ld8_bf16(h, nodeS * 64 + (kc - 4) * 32 + kq8, 1);
                else if (kc < 8) raw = *(const uint4*)&Tx1[(size_t)nodeS * 128 + (kc - 6) * 32 + kq8];
                else             raw = *(const uint4*)&Tx2[(size_t)nodeS * 128 + (kc - 8) * 32 + kq8];
            }
            *(uint4*)&As[(kc * 256 + tid) * 8] = raw;
        }
    }

    floatx4 acc[4][4];                   // [m-tile][gate]
    {
        float bv0 = biasP[w * 64 + 0 * 16 + (lane & 15)];
        float bv1 = biasP[w * 64 + 1 * 16 + (lane & 15)];
        float bv2 = biasP[w * 64 + 2 * 16 + (lane & 15)];
        float bv3 = biasP[w * 64 + 3 * 16 + (lane & 15)];
#pragma unroll
        for (int mt = 0; mt < 4; mt++) {
            acc[mt][0] = (floatx4){bv0, bv0, bv0, bv0};
            acc[mt][1] = (floatx4){bv1, bv1, bv1, bv1};
            acc[mt][2] = (floatx4){bv2, bv2, bv2, bv2};
            acc[mt][3] = (floatx4){bv3, bv3, bv3, bv3};
        }
    }

    __syncthreads();                     // staging complete (vmcnt drained)

#pragma unroll
    for (int kc = 0; kc < 10; kc++) {
        short8 aF[4];
#pragma unroll
        for (int mt = 0; mt < 4; mt++)
            aF[mt] = *(const short8*)&As[(kc * 256 + mt * 64 + lane) * 8];
        short8 bF[4];
#pragma unroll
        for (int g = 0; g < 4; g++)
            bF[g] = *(const short8*)&Wf[((kc * 16 + w * 4 + g) * 64 + lane) * 8];
#pragma unroll
        for (int mt = 0; mt < 4; mt++)
#pragma unroll
            for (int g = 0; g < 4; g++)
                acc[mt][g] = __builtin_amdgcn_mfma_f32_16x16x32_bf16(
                    aF[mt], bF[g], acc[mt][g], 0, 0, 0);
    }

    __syncthreads();   // As reads done -> safe to reuse as Hs

    ushort* Hs = As;   // 64 x 72 bf16 (9.2 KB) inside the dead As space

    // ---- LSTM epilogue, fully in-register (perm put all 4 gates here) ----
    const int cc = w * 16 + (lane & 15);
#pragma unroll
    for (int mt = 0; mt < 4; mt++) {
        const int m0 = mt * 16 + ((lane >> 4) * 4);
#pragma unroll
        for (int r = 0; r < 4; r++) {
            int ml = m0 + r;
            int node = base + ml;
            float gi = sigmoidf(acc[mt][0][r]);
            float gf = sigmoidf(acc[mt][1][r]);
            float gt = tanh_fast(acc[mt][2][r]);
            float go = sigmoidf(acc[mt][3][r]);
            float cv = (node < NN) ? ldin(cin, node * 64 + cc, f32) : 0.f;
            float c0 = gf * cv + gi * gt;
            float h0v = go * tanh_fast(c0);
            if (node < NN) {
                c0o[node * 64 + cc] = c0;
                h0o[node * 64 + cc] = h0v;
            }
            Hs[ml * 72 + cc] = f2bu(fmaxf(h0v, 0.f));
        }
    }
    __syncthreads();

    // ---- fused out = relu(h0) @ Wl + bl (8 MFMA per wave) ----
    float blv = ldin(bl, w * 16 + (lane & 15), f32);
    floatx4 oacc[4];
#pragma unroll
    for (int mt = 0; mt < 4; mt++) oacc[mt] = (floatx4){blv, blv, blv, blv};
#pragma unroll
    for (int kc2 = 0; kc2 < 2; kc2++) {
        short8 bW = *(const short8*)&WlF[((kc2 * 4 + w) * 64 + lane) * 8];
#pragma unroll
        for (int mt = 0; mt < 4; mt++) {
            short8 aH = *(const short8*)&Hs[(mt * 16 + (lane & 15)) * 72
                                            + kc2 * 32 + (lane >> 4) * 8];
            oacc[mt] = __builtin_amdgcn_mfma_f32_16x16x32_bf16(
                aH, bW, oacc[mt], 0, 0, 0);
        }
    }
#pragma unroll
    for (int mt = 0; mt < 4; mt++) {
        const int m0 = mt * 16 + ((lane >> 4) * 4);
#pragma unroll
        for (int r = 0; r < 4; r++) {
            int node = base + m0 + r;
            if (node < NN)
                outF[node * 64 + w * 16 + (lane & 15)] = oacc[mt][r];
        }
    }
}

extern "C" void kernel_launch(void* const* d_in, const int* in_sizes, int n_in,
                              void* d_out, int out_size, void* d_ws, size_t ws_size,
                              hipStream_t stream) {
    const void* x     = d_in[0];
    const int*  ei    = (const int*)d_in[1];
    const void* ew    = d_in[2];
    const void* h     = d_in[3];
    const void* c     = d_in[4];
    const void* Wx    = d_in[5];
    const void* bg    = d_in[6];
    const void* theta = d_in[7];
    const void* convb = d_in[8];
    const void* Wl    = d_in[9];
    const void* bl    = d_in[10];
    (void)in_sizes; (void)n_in; (void)out_size; (void)ws_size;

    // ws layout (4B words) — ~1.78 MB total
    float*  ws     = (float*)d_ws;
    int*    flag   = (int*)ws;                 // 64
    float*  dinv   = ws + 64;                  // 100000
    int*    rowptr = (int*)(ws + 100064);      // 100001 (pad to 100064)
    int*    gcntD  = (int*)(ws + 200128);      // 256
    int*    gcntS  = (int*)(ws + 200384);      // 256
    int*    bbaseD = (int*)(ws + 200640);      // 197 (pad 256)
    int*    bbaseS = (int*)(ws + 200896);      // 197
    int*    gcurD  = (int*)(ws + 201152);      // 256
    int*    gcurS  = (int*)(ws + 201408);      // 256
    float*  biasP  = ws + 400128;              // 256
    ushort* Wf     = (ushort*)(ws + 400384);   // 81920 ushort = 40960 words
    ushort* WlF    = (ushort*)(ws + 441344);   // 4096 ushort = 2048 words

    // d_out FP32: out [0,6.4M) | h0 [6.4M,12.8M) | c0 [12.8M,19.2M)  (words)
    float* outF = (float*)d_out;
    float* h0o  = outF + (size_t)NN * 64;
    float* c0o  = outF + (size_t)2 * NN * 64;
    // Tx1 bf16 aliases the out region; Tx2 bf16 aliases the c0 region —
    // node n occupies ushort [n*128, n*128+64) = bytes [n*256, n*256+128),
    // inside node n's own output slab.
    ushort* Tx1b = (ushort*)outF;
    ushort* Tx2b = (ushort*)c0o;
    // h0 region (6.4M words): recD [0,3.2M) + csr [3.2M,6.4M)
    //   recD written by k_part, read by k_build; csr written by k_build,
    //   read by gaths; whole region overwritten by k_gates h0 at the end.
    int2* recD = (int2*)h0o;
    int2* csr  = (int2*)(h0o + 3200000);
    // c0 region: recS [0,3.2M) — dead after k_build, then Tx2 overwrites.
    int2* recS = (int2*)c0o;

    k_sniff<<<1, 256, 0, stream>>>(x, flag);
    hipMemsetAsync(gcntD, 0, 512 * 4, stream);   // gcntD + gcntS

    k_count<<<(NE + 4095) / 4096, 256, 0, stream>>>(ei, gcntD, gcntS);
    k_scanb<<<1, 256, 0, stream>>>(gcntD, gcntS, bbaseD, bbaseS, gcurD, gcurS, rowptr);
    k_part<<<(NE + 2047) / 2048, 256, 0, stream>>>(ei, ew, gcurD, gcurS,
                                                   recD, recS, flag);
    k_build<<<NBUCK, 512, 0, stream>>>(recD, recS, bbaseD, bbaseS,
                                       rowptr, csr, dinv);
    k_wcat<<<336, 256, 0, stream>>>(Wx, theta, bg, convb, Wl, Wf, biasP, WlF, flag);

    k_gath<0><<<25000, 256, 0, stream>>>(rowptr, dinv, csr, h,    h, Tx1b, flag);
    k_gath<1><<<25000, 256, 0, stream>>>(rowptr, dinv, csr, Tx1b, h, Tx2b, flag);

    k_gates<<<(NN + 63) / 64, 256, 0, stream>>>(x, h, c, Tx1b, Tx2b,
                                                Wf, biasP, WlF, bl,
                                                outF, h0o, c0o, flag);
}

// Round 9
// 419.006 us; speedup vs baseline: 1.2216x; 1.0184x over previous
//
#include <hip/hip_runtime.h>
#include <hip/hip_bf16.h>

#define NN 100000
#define NE 1600000
#define INDIM 128
#define HID 64
#define BSH 9                      // 512 nodes per bucket
#define NBUCK 196                  // ceil(NN / 512)

typedef __hip_bfloat16 bf16;
typedef unsigned short ushort;
typedef unsigned int uint;
typedef __attribute__((ext_vector_type(8))) short short8;
typedef __attribute__((ext_vector_type(4))) float floatx4;

__device__ __forceinline__ float b2f(bf16 v) { return __bfloat162float(v); }
__device__ __forceinline__ float b2f_raw(ushort u) { return __uint_as_float(((uint)u) << 16); }
__device__ __forceinline__ ushort f2bu(float v) {
    bf16 t = __float2bfloat16(v);
    return *reinterpret_cast<ushort*>(&t);
}
// flag-aware input load: f32==1 -> fp32 tensor, else bf16 tensor
__device__ __forceinline__ float ldin(const void* p, int i, int f32) {
    return f32 ? ((const float*)p)[i] : b2f(((const bf16*)p)[i]);
}
__device__ __forceinline__ float sigmoidf(float x) { return 1.f / (1.f + __expf(-x)); }
__device__ __forceinline__ float tanh_fast(float x) {
    float e = __expf(2.f * x);
    return 1.f - 2.f / (e + 1.f);
}
__device__ __forceinline__ uint4 packf8(const float* f) {
    uint4 u;
    u.x = f2bu(f[0]) | ((uint)f2bu(f[1]) << 16);
    u.y = f2bu(f[2]) | ((uint)f2bu(f[3]) << 16);
    u.z = f2bu(f[4]) | ((uint)f2bu(f[5]) << 16);
    u.w = f2bu(f[6]) | ((uint)f2bu(f[7]) << 16);
    return u;
}
// 8 consecutive elements of a (bf16|fp32) tensor as packed bf16
__device__ __forceinline__ uint4 ld8_bf16(const void* p, int off, int f32) {
    if (!f32) return *(const uint4*)((const ushort*)p + off);
    const float* q = (const float*)p + off;
    float4 a = *(const float4*)q, b = *(const float4*)(q + 4);
    float f[8] = {a.x, a.y, a.z, a.w, b.x, b.y, b.z, b.w};
    return packf8(f);
}
// 4 consecutive edge weights
__device__ __forceinline__ void ld4w(const void* ew, int e0, int f32, float* w) {
    if (f32) {
        float4 v = *(const float4*)((const float*)ew + e0);
        w[0] = v.x; w[1] = v.y; w[2] = v.z; w[3] = v.w;
    } else {
        uint2 v = *(const uint2*)((const ushort*)ew + e0);
        w[0] = b2f_raw((ushort)(v.x & 0xffff)); w[1] = b2f_raw((ushort)(v.x >> 16));
        w[2] = b2f_raw((ushort)(v.y & 0xffff)); w[3] = b2f_raw((ushort)(v.y >> 16));
    }
}
// async global->LDS, 16 bytes per lane, zero VGPR round-trip
__device__ __forceinline__ void gl_lds16(const void* g, void* l) {
    __builtin_amdgcn_global_load_lds(
        (const __attribute__((address_space(1))) unsigned int*)g,
        (__attribute__((address_space(3))) unsigned int*)l, 16, 0, 0);
}

// ---------------- dtype sniffer ----------------------------------------
__global__ void k_sniff(const void* __restrict__ x, int* __restrict__ flag) {
    __shared__ int cnt;
    if (threadIdx.x == 0) cnt = 0;
    __syncthreads();
    const bf16* p = (const bf16*)x;
    int bad = 0;
    for (int i = threadIdx.x; i < 8192; i += 256) {
        float v = b2f(p[i]);
        if (!(fabsf(v) < 1e6f)) bad++;
    }
    atomicAdd(&cnt, bad);
    __syncthreads();
    if (threadIdx.x == 0) flag[0] = (cnt > 32) ? 1 : 0;
}

// ---------------- pass 1: per-bucket counts (dst bins + src bins) ------
__global__ __launch_bounds__(256)
void k_count(const int* __restrict__ ei, int* __restrict__ gcntD,
             int* __restrict__ gcntS) {
    __shared__ int hD[NBUCK], hS[NBUCK];
    for (int i = threadIdx.x; i < NBUCK; i += 256) { hD[i] = 0; hS[i] = 0; }
    __syncthreads();
    int e0 = (blockIdx.x * 256 + threadIdx.x) * 16;
    if (e0 < NE) {
        if (e0 + 16 <= NE) {
#pragma unroll
            for (int q = 0; q < 4; q++) {
                int4 s4 = *(const int4*)(ei + e0 + q * 4);
                int4 d4 = *(const int4*)(ei + NE + e0 + q * 4);
                int ss[4] = {s4.x, s4.y, s4.z, s4.w};
                int dd[4] = {d4.x, d4.y, d4.z, d4.w};
#pragma unroll
                for (int j = 0; j < 4; j++)
                    if (ss[j] != dd[j]) {
                        atomicAdd(hD + (dd[j] >> BSH), 1);
                        atomicAdd(hS + (ss[j] >> BSH), 1);
                    }
            }
        } else {
            for (int e = e0; e < NE; e++) {
                int s = ei[e], d = ei[NE + e];
                if (s != d) {
                    atomicAdd(hD + (d >> BSH), 1);
                    atomicAdd(hS + (s >> BSH), 1);
                }
            }
        }
    }
    __syncthreads();
    for (int i = threadIdx.x; i < NBUCK; i += 256) {
        if (hD[i]) atomicAdd(gcntD + i, hD[i]);
        if (hS[i]) atomicAdd(gcntS + i, hS[i]);
    }
}

// ---------------- pass 2: scan bucket counts -> bases + cursors --------
__global__ __launch_bounds__(256)
void k_scanb(const int* __restrict__ gcntD, const int* __restrict__ gcntS,
             int* __restrict__ bbaseD, int* __restrict__ bbaseS,
             int* __restrict__ gcurD, int* __restrict__ gcurS,
             int* __restrict__ rowptr) {
    __shared__ int sh[256];
    const int t = threadIdx.x;
    int v = (t < NBUCK) ? gcntD[t] : 0;
    sh[t] = v; __syncthreads();
    for (int off = 1; off < 256; off <<= 1) {
        int u = (t >= off) ? sh[t - off] : 0;
        __syncthreads(); sh[t] += u; __syncthreads();
    }
    if (t < NBUCK) { int e = sh[t] - v; bbaseD[t] = e; gcurD[t] = e; }
    if (t == 255) { bbaseD[NBUCK] = sh[255]; rowptr[NN] = sh[255]; }
    __syncthreads();
    int v2 = (t < NBUCK) ? gcntS[t] : 0;
    sh[t] = v2; __syncthreads();
    for (int off = 1; off < 256; off <<= 1) {
        int u = (t >= off) ? sh[t - off] : 0;
        __syncthreads(); sh[t] += u; __syncthreads();
    }
    if (t < NBUCK) { int e = sh[t] - v2; bbaseS[t] = e; gcurS[t] = e; }
    if (t == 255) bbaseS[NBUCK] = sh[255];
}

// ---------------- pass 3: partition edges into bucketed record streams -
// recD = {src | dlocal<<17, w}  binned by dst>>BSH
// recS = {slocal, w}            binned by src>>BSH
__global__ __launch_bounds__(256)
void k_part(const int* __restrict__ ei, const void* __restrict__ ew,
            int* __restrict__ gcurD, int* __restrict__ gcurS,
            int2* __restrict__ recD, int2* __restrict__ recS,
            const int* __restrict__ flagp) {
    const int f32 = flagp[0];
    __shared__ int cD[NBUCK], cS[NBUCK], bD[NBUCK], bS[NBUCK];
    for (int i = threadIdx.x; i < NBUCK; i += 256) { cD[i] = 0; cS[i] = 0; }
    __syncthreads();
    const int e0 = (blockIdx.x * 256 + threadIdx.x) * 8;
    int s[8], d[8], rD[8], rS[8];
    float w[8];
    bool act[8];
    if (e0 + 8 <= NE) {
        int4 sa = *(const int4*)(ei + e0), sb = *(const int4*)(ei + e0 + 4);
        int4 da = *(const int4*)(ei + NE + e0), db = *(const int4*)(ei + NE + e0 + 4);
        s[0]=sa.x; s[1]=sa.y; s[2]=sa.z; s[3]=sa.w;
        s[4]=sb.x; s[5]=sb.y; s[6]=sb.z; s[7]=sb.w;
        d[0]=da.x; d[1]=da.y; d[2]=da.z; d[3]=da.w;
        d[4]=db.x; d[5]=db.y; d[6]=db.z; d[7]=db.w;
        ld4w(ew, e0, f32, w); ld4w(ew, e0 + 4, f32, w + 4);
#pragma unroll
        for (int j = 0; j < 8; j++) act[j] = (s[j] != d[j]);
    } else {
#pragma unroll
        for (int j = 0; j < 8; j++) {
            int e = e0 + j;
            if (e < NE) {
                s[j] = ei[e]; d[j] = ei[NE + e]; w[j] = ldin(ew, e, f32);
                act[j] = (s[j] != d[j]);
            } else { s[j] = 0; d[j] = 0; w[j] = 0.f; act[j] = false; }
        }
    }
#pragma unroll
    for (int j = 0; j < 8; j++)
        if (act[j]) {
            rD[j] = atomicAdd(cD + (d[j] >> BSH), 1);
            rS[j] = atomicAdd(cS + (s[j] >> BSH), 1);
        }
    __syncthreads();
    for (int i = threadIdx.x; i < NBUCK; i += 256) {
        bD[i] = cD[i] ? atomicAdd(gcurD + i, cD[i]) : 0;
        bS[i] = cS[i] ? atomicAdd(gcurS + i, cS[i]) : 0;
    }
    __syncthreads();
#pragma unroll
    for (int j = 0; j < 8; j++)
        if (act[j]) {
            int2 pd; pd.x = s[j] | ((d[j] & 511) << 17); pd.y = __float_as_int(w[j]);
            recD[bD[d[j] >> BSH] + rD[j]] = pd;
            int2 ps; ps.x = s[j] & 511; ps.y = __float_as_int(w[j]);
            recS[bS[s[j] >> BSH] + rS[j]] = ps;
        }
}

// ---------------- pass 4: per-bucket build (all node-indexed work in LDS)
// compact CSR + rowptr + dinv, coalesced global writes.
__global__ __launch_bounds__(512)
void k_build(const int2* __restrict__ recD, const int2* __restrict__ recS,
             const int* __restrict__ bbaseD, const int* __restrict__ bbaseS,
             int* __restrict__ rowptr, int2* __restrict__ csr,
             float* __restrict__ dinv) {
    __shared__ int cnt[512], sh[512], cur[512];
    __shared__ float degf[512];
    const int t = threadIdx.x, b = blockIdx.x;
    cnt[t] = 0; degf[t] = 0.f;
    __syncthreads();
    const int dbase = bbaseD[b], dend = bbaseD[b + 1];
    const int sbase = bbaseS[b], send = bbaseS[b + 1];
    const int nD = dend - dbase, nS = send - sbase;
    const int2* rd = recD + dbase;
    const int2* rs = recS + sbase;
    for (int i = t; i < nD; i += 512) atomicAdd(cnt + (rd[i].x >> 17), 1);
    for (int i = t; i < nS; i += 512) atomicAdd(degf + rs[i].x, __int_as_float(rs[i].y));
    __syncthreads();
    const int own = cnt[t];
    sh[t] = own; __syncthreads();
    for (int off = 1; off < 512; off <<= 1) {
        int u = (t >= off) ? sh[t - off] : 0;
        __syncthreads(); sh[t] += u; __syncthreads();
    }
    const int rstart = dbase + sh[t] - own;
    cur[t] = rstart;
    const int node = (b << BSH) + t;
    if (node < NN) {
        rowptr[node] = rstart;
        float dg = degf[t];
        dinv[node] = dg > 0.f ? rsqrtf(dg) : 0.f;
    }
    __syncthreads();
    for (int i = t; i < nD; i += 512) {
        int2 r = rd[i];
        int pos = atomicAdd(cur + (r.x >> 17), 1);
        int2 o; o.x = r.x & 0x1FFFF; o.y = r.y;
        csr[pos] = o;
    }
}

// ---------------- gather SpMM: one wave per dst, register accumulate ---
// agg = -dinv[dst] * sum_e dinv[src_e] * w_e * z[src_e]
// Lanes cooperatively load <=64 csr entries in ONE coalesced read and
// pre-scale dinv[src]*w lane-parallel; per-edge values are shfl-broadcast,
// so the z-row loads issue back-to-back (no csr->z dependent chain).
// MODE 0: z = h (flag dtype, stride 64)   -> Tx1 = agg, bf16 stride-128
// MODE 1: z = Tx1 (bf16 stride-128 rows)  -> Tx2 = 2*agg - h, bf16 stride-128
template<int MODE>
__global__ __launch_bounds__(256)
void k_gath(const int* __restrict__ rowptr, const float* __restrict__ dinv,
            const int2* __restrict__ csr, const void* __restrict__ zin,
            const void* __restrict__ hin, ushort* __restrict__ outv,
            const int* __restrict__ flagp) {
    const int f32 = flagp[0];
    int n = (blockIdx.x * 256 + threadIdx.x) >> 6;   // dst node
    int lane = threadIdx.x & 63;
    if (n >= NN) return;
    int b0 = rowptr[n], e0r = rowptr[n + 1];
    int cnt = e0r - b0;
    const int2* row = csr + b0;
    float acc = 0.f;
#define ZLD(sidx) (MODE == 0 ? ldin(zin, (sidx) * 64 + lane, f32) \
                             : b2f_raw(((const ushort*)zin)[(size_t)(sidx) * 128 + lane]))
    for (int ib = 0; ib < cnt; ib += 64) {
        int idx = ib + lane;
        int2 p;
        if (idx < cnt) p = row[idx];
        else { p.x = 0; p.y = 0; }
        float sw = dinv[p.x] * __int_as_float(p.y);   // 0 for inactive lanes
        int m = cnt - ib; if (m > 64) m = 64;
        int m4 = (m + 3) & ~3;
        for (int e = 0; e < m4; e += 4) {
            int   s0 = __shfl(p.x, e),     s1 = __shfl(p.x, e + 1);
            int   s2 = __shfl(p.x, e + 2), s3 = __shfl(p.x, e + 3);
            float w0 = __shfl(sw, e),      w1 = __shfl(sw, e + 1);
            float w2 = __shfl(sw, e + 2),  w3 = __shfl(sw, e + 3);
            float z0 = ZLD(s0), z1 = ZLD(s1), z2 = ZLD(s2), z3 = ZLD(s3);
            acc = fmaf(w0, z0, acc);
            acc = fmaf(w1, z1, acc);
            acc = fmaf(w2, z2, acc);
            acc = fmaf(w3, z3, acc);
        }
    }
#undef ZLD
    float r = -dinv[n] * acc;
    if (MODE == 0) {
        outv[(size_t)n * 128 + lane] = f2bu(r);
    } else {
        float hv = ldin(hin, n * 64 + lane, f32);        // coalesced
        outv[(size_t)n * 128 + lane] = f2bu(2.f * r - hv);
    }
}

// ---------------- pre-swizzle weights into MFMA fragment order ---------
// Wf: [kc 0..9][t 0..15][lane 0..63][j 0..7] bf16, element =
//     W[r = kc*32 + (lane>>4)*8 + j][o = 16t + (lane&15)] with column perm
//     o = 16t+(l&15): gate g = t&3, cc = (t>>2)*16 + (lane&15)
// WlF: [kc2 0..1][t 0..3][lane][j], Wl[k = kc2*32+(l>>4)*8+j][n = 16t+(l&15)]
// biasP[o]: permuted bias
__global__ void k_wcat(const void* __restrict__ Wx, const void* __restrict__ theta,
                       const void* __restrict__ bg, const void* __restrict__ convb,
                       const void* __restrict__ Wl,
                       ushort* __restrict__ Wf, float* __restrict__ biasP,
                       ushort* __restrict__ WlF, const int* __restrict__ flagp) {
    const int f32 = flagp[0];
    int gid = blockIdx.x * 256 + threadIdx.x;   // 336 blocks * 256 = 86016
    if (gid < 81920) {
        int j = gid & 7, l = (gid >> 3) & 63, tile = gid >> 9;
        int kc = tile >> 4, t = tile & 15;
        int r = kc * 32 + ((l >> 4) * 8) + j;
        int g = t & 3;
        int cc = (t >> 2) * 16 + (l & 15);
        float v;
        if (r < 128) {
            v = ldin(Wx, (g * 128 + r) * 64 + cc, f32);
        } else {
            int k3 = (r - 128) >> 6, rr = (r - 128) & 63;
            v = ldin(theta, ((g * 3 + k3) * 64 + rr) * 64 + cc, f32);
        }
        Wf[gid] = f2bu(v);
        if (gid < 256) {
            int o = gid;
            int gg = (o >> 4) & 3;
            int cc2 = (o >> 6) * 16 + (o & 15);
            biasP[o] = ldin(bg, gg * 64 + cc2, f32) + ldin(convb, gg * 64 + cc2, f32);
        }
    } else {
        int gid2 = gid - 81920;                  // [0, 4096)
        int j = gid2 & 7, l = (gid2 >> 3) & 63, tile2 = gid2 >> 9;
        int kc2 = tile2 >> 2, t = tile2 & 3;
        int k = kc2 * 32 + ((l >> 4) * 8) + j;
        int n = t * 16 + (l & 15);
        WlF[gid2] = f2bu(ldin(Wl, k * 64 + n, f32));
    }
}

// ---------------- MFMA gate GEMM [32 nodes x 256 cols] + LSTM + out ----
// F rows: 0-127 x | 128-191 h | 192-255 Tx1 | 256-319 Tx2
// 32-node M-tile: A-panel = 32 x 320 bf16 = 20 KB LDS -> 8 blocks/CU
// (2x the R7 wave residency). Staged up-front via global_load_lds
// (16B/lane, zero VGPR): 5 fire-and-forget iterations/thread, one
// barrier, then 80 MFMA/wave with no further syncs. `c` operand is
// prefetched into registers BEFORE the K-loop so the epilogue's
// dependent load latency hides under the MFMAs. Hs reuses dead As.
// Slot s (of 1280): kc=s>>7, b=s&127, mt=b>>6, l=b&63 ->
//   node base+mt*16+(l&15), cols kc*32+(l>>4)*8; thread stages slot
//   it*256+tid (LDS dest = linear lane*16 — required gl_lds layout).
// Aliasing: Tx1 lives in `out`, Tx2 in `c0` (per-node slabs); all
// aliased reads complete at the pre-K-loop barrier (vmcnt drain).
__global__ __launch_bounds__(256)
void k_gates(const void* __restrict__ x, const void* __restrict__ h,
             const void* __restrict__ cin,
             const ushort* __restrict__ Tx1, const ushort* __restrict__ Tx2,
             const ushort* __restrict__ Wf, const float* __restrict__ biasP,
             const ushort* __restrict__ WlF, const void* __restrict__ bl,
             float* __restrict__ outF, float* __restrict__ h0o,
             float* __restrict__ c0o, const int* __restrict__ flagp) {
    const int f32 = flagp[0];
    __shared__ ushort As[10 * 128 * 8];  // 20 KB; reused as Hs after K-loop
    const int tid = threadIdx.x;
    const int lane = tid & 63;
    const int w = tid >> 6;              // wave 0..3
    const int base = blockIdx.x * 32;
    const int cc = w * 16 + (lane & 15);

    // ---- prefetch c operand (epilogue) — overlaps staging + MFMA ----
    float cvv[2][4];
#pragma unroll
    for (int mt = 0; mt < 2; mt++) {
        const int m0 = mt * 16 + ((lane >> 4) * 4);
#pragma unroll
        for (int r = 0; r < 4; r++) {
            int node = base + m0 + r;
            cvv[mt][r] = (node < NN) ? ldin(cin, node * 64 + cc, f32) : 0.f;
        }
    }

    // ---- stage A-panel: 5 iterations, slot = it*256 + tid ----
    if (!f32) {
#pragma unroll
        for (int it = 0; it < 5; it++) {
            int s = it * 256 + tid;
            int kc = s >> 7, b = s & 127;
            int node = base + ((b >> 6) << 4) + (b & 15);
            int kq8 = ((b >> 4) & 3) * 8;
            if (node < NN) {
                const ushort* g;
                if (kc < 4)      g = (const ushort*)x + (size_t)node * 128 + kc * 32 + kq8;
                else if (kc < 6) g = (const ushort*)h + (size_t)node * 64 + (kc - 4) * 32 + kq8;
                else if (kc < 8) g = Tx1 + (size_t)node * 128 + (kc - 6) * 32 + kq8;
                else             g = Tx2 + (size_t)node * 128 + (kc - 8) * 32 + kq8;
                gl_lds16(g, &As[s * 8]);
            }
        }
    } else {
#pragma unroll
        for (int it = 0; it < 5; it++) {
            int s = it * 256 + tid;
            int kc = s >> 7, b = s & 127;
            int node = base + ((b >> 6) << 4) + (b & 15);
            int kq8 = ((b >> 4) & 3) * 8;
            uint4 raw = {0, 0, 0, 0};
            if (node < NN) {
                if (kc < 4)      raw = ld8_bf16(x, node * 128 + kc * 32 + kq8, 1);
                else if (kc < 6) raw = ld8_bf16(h, node * 64 + (kc - 4) * 32 + kq8, 1);
                else if (kc < 8) raw = *(const uint4*)&Tx1[(size_t)node * 128 + (kc - 6) * 32 + kq8];
                else             raw = *(const uint4*)&Tx2[(size_t)node * 128 + (kc - 8) * 32 + kq8];
            }
            *(uint4*)&As[s * 8] = raw;
        }
    }

    floatx4 acc[2][4];                   // [m-tile][gate]
    {
        float bv0 = biasP[w * 64 + 0 * 16 + (lane & 15)];
        float bv1 = biasP[w * 64 + 1 * 16 + (lane & 15)];
        float bv2 = biasP[w * 64 + 2 * 16 + (lane & 15)];
        float bv3 = biasP[w * 64 + 3 * 16 + (lane & 15)];
#pragma unroll
        for (int mt = 0; mt < 2; mt++) {
            acc[mt][0] = (floatx4){bv0, bv0, bv0, bv0};
            acc[mt][1] = (floatx4){bv1, bv1, bv1, bv1};
            acc[mt][2] = (floatx4){bv2, bv2, bv2, bv2};
            acc[mt][3] = (floatx4){bv3, bv3, bv3, bv3};
        }
    }

    __syncthreads();                     // staging complete (vmcnt drained)

#pragma unroll
    for (int kc = 0; kc < 10; kc++) {
        short8 aF[2];
#pragma unroll
        for (int mt = 0; mt < 2; mt++)
            aF[mt] = *(const short8*)&As[(kc * 128 + mt * 64 + lane) * 8];
        short8 bF[4];
#pragma unroll
        for (int g = 0; g < 4; g++)
            bF[g] = *(const short8*)&Wf[((kc * 16 + w * 4 + g) * 64 + lane) * 8];
#pragma unroll
        for (int mt = 0; mt < 2; mt++)
#pragma unroll
            for (int g = 0; g < 4; g++)
                acc[mt][g] = __builtin_amdgcn_mfma_f32_16x16x32_bf16(
                    aF[mt], bF[g], acc[mt][g], 0, 0, 0);
    }

    __syncthreads();   // As reads done -> safe to reuse as Hs

    ushort* Hs = As;   // 32 x 72 bf16 (4.6 KB) inside the dead As space

    // ---- LSTM epilogue, fully in-register (perm put all 4 gates here) ----
#pragma unroll
    for (int mt = 0; mt < 2; mt++) {
        const int m0 = mt * 16 + ((lane >> 4) * 4);
#pragma unroll
        for (int r = 0; r < 4; r++) {
            int ml = m0 + r;
            int node = base + ml;
            float gi = sigmoidf(acc[mt][0][r]);
            float gf = sigmoidf(acc[mt][1][r]);
            float gt = tanh_fast(acc[mt][2][r]);
            float go = sigmoidf(acc[mt][3][r]);
            float c0 = gf * cvv[mt][r] + gi * gt;
            float h0v = go * tanh_fast(c0);
            if (node < NN) {
                c0o[node * 64 + cc] = c0;
                h0o[node * 64 + cc] = h0v;
            }
            Hs[ml * 72 + cc] = f2bu(fmaxf(h0v, 0.f));
        }
    }
    __syncthreads();

    // ---- fused out = relu(h0) @ Wl + bl (4 MFMA per wave) ----
    float blv = ldin(bl, w * 16 + (lane & 15), f32);
    floatx4 oacc[2];
#pragma unroll
    for (int mt = 0; mt < 2; mt++) oacc[mt] = (floatx4){blv, blv, blv, blv};
#pragma unroll
    for (int kc2 = 0; kc2 < 2; kc2++) {
        short8 bW = *(const short8*)&WlF[((kc2 * 4 + w) * 64 + lane) * 8];
#pragma unroll
        for (int mt = 0; mt < 2; mt++) {
            short8 aH = *(const short8*)&Hs[(mt * 16 + (lane & 15)) * 72
                                            + kc2 * 32 + (lane >> 4) * 8];
            oacc[mt] = __builtin_amdgcn_mfma_f32_16x16x32_bf16(
                aH, bW, oacc[mt], 0, 0, 0);
        }
    }
#pragma unroll
    for (int mt = 0; mt < 2; mt++) {
        const int m0 = mt * 16 + ((lane >> 4) * 4);
#pragma unroll
        for (int r = 0; r < 4; r++) {
            int node = base + m0 + r;
            if (node < NN)
                outF[node * 64 + w * 16 + (lane & 15)] = oacc[mt][r];
        }
    }
}

extern "C" void kernel_launch(void* const* d_in, const int* in_sizes, int n_in,
                              void* d_out, int out_size, void* d_ws, size_t ws_size,
                              hipStream_t stream) {
    const void* x     = d_in[0];
    const int*  ei    = (const int*)d_in[1];
    const void* ew    = d_in[2];
    const void* h     = d_in[3];
    const void* c     = d_in[4];
    const void* Wx    = d_in[5];
    const void* bg    = d_in[6];
    const void* theta = d_in[7];
    const void* convb = d_in[8];
    const void* Wl    = d_in[9];
    const void* bl    = d_in[10];
    (void)in_sizes; (void)n_in; (void)out_size; (void)ws_size;

    // ws layout (4B words) — ~1.78 MB total
    float*  ws     = (float*)d_ws;
    int*    flag   = (int*)ws;                 // 64
    float*  dinv   = ws + 64;                  // 100000
    int*    rowptr = (int*)(ws + 100064);      // 100001 (pad to 100064)
    int*    gcntD  = (int*)(ws + 200128);      // 256
    int*    gcntS  = (int*)(ws + 200384);      // 256
    int*    bbaseD = (int*)(ws + 200640);      // 197 (pad 256)
    int*    bbaseS = (int*)(ws + 200896);      // 197
    int*    gcurD  = (int*)(ws + 201152);      // 256
    int*    gcurS  = (int*)(ws + 201408);      // 256
    float*  biasP  = ws + 400128;              // 256
    ushort* Wf     = (ushort*)(ws + 400384);   // 81920 ushort = 40960 words
    ushort* WlF    = (ushort*)(ws + 441344);   // 4096 ushort = 2048 words

    // d_out FP32: out [0,6.4M) | h0 [6.4M,12.8M) | c0 [12.8M,19.2M)  (words)
    float* outF = (float*)d_out;
    float* h0o  = outF + (size_t)NN * 64;
    float* c0o  = outF + (size_t)2 * NN * 64;
    // Tx1 bf16 aliases the out region; Tx2 bf16 aliases the c0 region —
    // node n occupies ushort [n*128, n*128+64) = bytes [n*256, n*256+128),
    // inside node n's own output slab.
    ushort* Tx1b = (ushort*)outF;
    ushort* Tx2b = (ushort*)c0o;
    // h0 region (6.4M words): recD [0,3.2M) + csr [3.2M,6.4M)
    //   recD written by k_part, read by k_build; csr written by k_build,
    //   read by gaths; whole region overwritten by k_gates h0 at the end.
    int2* recD = (int2*)h0o;
    int2* csr  = (int2*)(h0o + 3200000);
    // c0 region: recS [0,3.2M) — dead after k_build, then Tx2 overwrites.
    int2* recS = (int2*)c0o;

    k_sniff<<<1, 256, 0, stream>>>(x, flag);
    hipMemsetAsync(gcntD, 0, 512 * 4, stream);   // gcntD + gcntS

    k_count<<<(NE + 4095) / 4096, 256, 0, stream>>>(ei, gcntD, gcntS);
    k_scanb<<<1, 256, 0, stream>>>(gcntD, gcntS, bbaseD, bbaseS, gcurD, gcurS, rowptr);
    k_part<<<(NE + 2047) / 2048, 256, 0, stream>>>(ei, ew, gcurD, gcurS,
                                                   recD, recS, flag);
    k_build<<<NBUCK, 512, 0, stream>>>(recD, recS, bbaseD, bbaseS,
                                       rowptr, csr, dinv);
    k_wcat<<<336, 256, 0, stream>>>(Wx, theta, bg, convb, Wl, Wf, biasP, WlF, flag);

    k_gath<0><<<25000, 256, 0, stream>>>(rowptr, dinv, csr, h,    h, Tx1b, flag);
    k_gath<1><<<25000, 256, 0, stream>>>(rowptr, dinv, csr, Tx1b, h, Tx2b, flag);

    k_gates<<<(NN + 31) / 32, 256, 0, stream>>>(x, h, c, Tx1b, Tx2b,
                                                Wf, biasP, WlF, bl,
                                                outF, h0o, c0o, flag);
}